// Round 4
// baseline (1447.513 us; speedup 1.0000x reference)
//
#include <hip/hip_runtime.h>
#include <math.h>
#include <stdint.h>

#define B_ 2
#define H_ 8
#define C_ 2048
#define E_ 1024
#define D_ 64
#define KP_ 8
#define P_ 16
#define HD_ 512              // H*D
#define ROWS_ 32768          // B*H*C
#define M_ 4096              // B*C

typedef __bf16 bf16x8 __attribute__((ext_vector_type(8)));
typedef float f32x4 __attribute__((ext_vector_type(4)));
typedef uint16_t u16x8 __attribute__((ext_vector_type(8)));

__device__ inline uint16_t f2bf(float f) {
    union { float f; uint32_t u; } v; v.f = f;
    uint32_t u = v.u + 0x7FFF + ((v.u >> 16) & 1);   // RNE
    return (uint16_t)(u >> 16);
}
__device__ inline float bf2f(uint16_t h) {
    union { uint32_t u; float f; } v; v.u = ((uint32_t)h) << 16;
    return v.f;
}

// async global->LDS, 16B per lane; LDS dest = wave-uniform base + lane*16
__device__ inline void gload16(const uint16_t* g, uint16_t* l) {
    __builtin_amdgcn_global_load_lds(
        (const __attribute__((address_space(1))) void*)g,
        (__attribute__((address_space(3))) void*)l, 16, 0, 0);
}

// ---------------------------------------------------------------------------
// convert x (4096x1024 fp32) -> bf16
// ---------------------------------------------------------------------------
__global__ __launch_bounds__(256) void convert_x_kernel(
    const float* __restrict__ in, uint16_t* __restrict__ out)
{
    const int i = (blockIdx.x * 256 + threadIdx.x) * 8;
    const float4 a = *(const float4*)(in + i);
    const float4 b = *(const float4*)(in + i + 4);
    u16x8 o;
    o[0] = f2bf(a.x); o[1] = f2bf(a.y); o[2] = f2bf(a.z); o[3] = f2bf(a.w);
    o[4] = f2bf(b.x); o[5] = f2bf(b.y); o[6] = f2bf(b.z); o[7] = f2bf(b.w);
    *(u16x8*)(out + i) = o;
}

// ---------------------------------------------------------------------------
// transpose-convert weights.  z=0,1,2: Wq/Wk/Wv (1024x512) -> Wall rows
// [z*512, z*512+512) of a 1536x1024 bf16 matrix, Q/K scaled by 1/8 (exact).
// z=3: Wu (512x1024) -> Wut (1024x512).
// ---------------------------------------------------------------------------
__global__ __launch_bounds__(256) void convert_wt_kernel(
    const float* __restrict__ Wq, const float* __restrict__ Wk,
    const float* __restrict__ Wv, const float* __restrict__ Wu,
    uint16_t* __restrict__ Wall, uint16_t* __restrict__ Wut)
{
    const int z = blockIdx.z;
    const float* in; uint16_t* out; int R, Cc; float scale;
    if (z == 0)      { in = Wq; out = Wall;                 R = E_;  Cc = HD_; scale = 0.125f; }
    else if (z == 1) { in = Wk; out = Wall + 512 * 1024;    R = E_;  Cc = HD_; scale = 0.125f; }
    else if (z == 2) { in = Wv; out = Wall + 1024 * 1024;   R = E_;  Cc = HD_; scale = 1.0f; }
    else             { in = Wu; out = Wut;                  R = HD_; Cc = E_;  scale = 1.0f; }
    const int tiles_x = Cc >> 5;
    const int tx = blockIdx.x % tiles_x;
    const int ty = blockIdx.x / tiles_x;
    const int r0 = ty * 32, c0 = tx * 32;
    __shared__ float t[32][33];
    const int lx = threadIdx.x & 31, ly = threadIdx.x >> 5;
#pragma unroll
    for (int i = 0; i < 4; ++i)
        t[ly * 4 + i][lx] = in[(size_t)(r0 + ly * 4 + i) * Cc + c0 + lx];
    __syncthreads();
#pragma unroll
    for (int i = 0; i < 4; ++i)
        out[(size_t)(c0 + ly * 4 + i) * R + r0 + lx] = f2bf(t[lx][ly * 4 + i] * scale);
}

// ---------------------------------------------------------------------------
// Fused QKV GEMM (MFMA bf16): xb (4096x1024) @ Wall^T-rows (1536x1024)
// -> Q/K/V bf16 in (b,h,c,d) layout.  One dispatch, 384 blocks.
// ---------------------------------------------------------------------------
__global__ __launch_bounds__(256) void gemm_qkv_kernel(
    const uint16_t* __restrict__ xb, const uint16_t* __restrict__ Wall,
    uint16_t* __restrict__ Qt, uint16_t* __restrict__ Kt,
    uint16_t* __restrict__ Vt)
{
    const int K = E_;                       // 1024
    const int m0 = blockIdx.y * 128;
    const int n0 = blockIdx.x * 128;        // 0..1535
    const int z = n0 >> 9;
    uint16_t* __restrict__ Out = (z == 0) ? Qt : (z == 1) ? Kt : Vt;

    __shared__ __align__(16) uint16_t As[128 * 32];
    __shared__ __align__(16) uint16_t Bs[128 * 32];

    const int tid = threadIdx.x;
    const int w = tid >> 6, lane = tid & 63;
    const int wm = w & 1, wn = w >> 1;

    f32x4 acc[4][4] = {};

    const int r0s = (w * 2 + 0) * 16 + (lane >> 2);
    const int r1s = (w * 2 + 1) * 16 + (lane >> 2);
    const int ko  = (lane & 3) * 8;
    const uint16_t* gA0 = xb + (size_t)(m0 + r0s) * K + ko;
    const uint16_t* gA1 = xb + (size_t)(m0 + r1s) * K + ko;
    const uint16_t* gB0 = Wall + (size_t)(n0 + r0s) * K + ko;
    const uint16_t* gB1 = Wall + (size_t)(n0 + r1s) * K + ko;
    uint16_t* lA0 = &As[(w * 2 + 0) * 512];
    uint16_t* lA1 = &As[(w * 2 + 1) * 512];
    uint16_t* lB0 = &Bs[(w * 2 + 0) * 512];
    uint16_t* lB1 = &Bs[(w * 2 + 1) * 512];

    const int fr = lane & 15;
    const int fk = (lane >> 4) * 8;

    for (int k0 = 0; k0 < K; k0 += 32) {
        __syncthreads();
        gload16(gA0 + k0, lA0);
        gload16(gA1 + k0, lA1);
        gload16(gB0 + k0, lB0);
        gload16(gB1 + k0, lB1);
        __syncthreads();
        bf16x8 af[4], bf[4];
#pragma unroll
        for (int t = 0; t < 4; ++t) {
            af[t] = *(const bf16x8*)&As[(wm * 64 + t * 16 + fr) * 32 + fk];
            bf[t] = *(const bf16x8*)&Bs[(wn * 64 + t * 16 + fr) * 32 + fk];
        }
#pragma unroll
        for (int mt = 0; mt < 4; ++mt)
#pragma unroll
            for (int nt = 0; nt < 4; ++nt)
                acc[mt][nt] = __builtin_amdgcn_mfma_f32_16x16x32_bf16(
                    af[mt], bf[nt], acc[mt][nt], 0, 0, 0);
    }

#pragma unroll
    for (int mt = 0; mt < 4; ++mt) {
#pragma unroll
        for (int nt = 0; nt < 4; ++nt) {
            const int nl = (n0 & 511) + wn * 64 + nt * 16 + fr;
            const int h = nl >> 6, d = nl & 63;
#pragma unroll
            for (int r = 0; r < 4; ++r) {
                const int m = m0 + wm * 64 + mt * 16 + (lane >> 4) * 4 + r;
                const int b = m >> 11, c = m & (C_ - 1);
                Out[(((size_t)(b * H_ + h) * C_ + c) << 6) + d] =
                    f2bf(acc[mt][nt][r]);
            }
        }
    }
}

// ---------------------------------------------------------------------------
// GEMM 2 (MFMA bf16): united (4096x512) @ Wu^T-rows (1024x512) + bu
// ---------------------------------------------------------------------------
__global__ __launch_bounds__(256) void gemm_out_kernel(
    const uint16_t* __restrict__ U, const uint16_t* __restrict__ Wut,
    const float* __restrict__ bu, float* __restrict__ out)
{
    const int K = HD_;                      // 512
    const int m0 = blockIdx.y * 128;
    const int n0 = blockIdx.x * 128;        // N=1024

    __shared__ __align__(16) uint16_t As[128 * 32];
    __shared__ __align__(16) uint16_t Bs[128 * 32];

    const int tid = threadIdx.x;
    const int w = tid >> 6, lane = tid & 63;
    const int wm = w & 1, wn = w >> 1;

    f32x4 acc[4][4] = {};

    const int r0s = (w * 2 + 0) * 16 + (lane >> 2);
    const int r1s = (w * 2 + 1) * 16 + (lane >> 2);
    const int ko  = (lane & 3) * 8;
    const uint16_t* gA0 = U + (size_t)(m0 + r0s) * K + ko;
    const uint16_t* gA1 = U + (size_t)(m0 + r1s) * K + ko;
    const uint16_t* gB0 = Wut + (size_t)(n0 + r0s) * K + ko;
    const uint16_t* gB1 = Wut + (size_t)(n0 + r1s) * K + ko;
    uint16_t* lA0 = &As[(w * 2 + 0) * 512];
    uint16_t* lA1 = &As[(w * 2 + 1) * 512];
    uint16_t* lB0 = &Bs[(w * 2 + 0) * 512];
    uint16_t* lB1 = &Bs[(w * 2 + 1) * 512];

    const int fr = lane & 15;
    const int fk = (lane >> 4) * 8;

    for (int k0 = 0; k0 < K; k0 += 32) {
        __syncthreads();
        gload16(gA0 + k0, lA0);
        gload16(gA1 + k0, lA1);
        gload16(gB0 + k0, lB0);
        gload16(gB1 + k0, lB1);
        __syncthreads();
        bf16x8 af[4], bf[4];
#pragma unroll
        for (int t = 0; t < 4; ++t) {
            af[t] = *(const bf16x8*)&As[(wm * 64 + t * 16 + fr) * 32 + fk];
            bf[t] = *(const bf16x8*)&Bs[(wn * 64 + t * 16 + fr) * 32 + fk];
        }
#pragma unroll
        for (int mt = 0; mt < 4; ++mt)
#pragma unroll
            for (int nt = 0; nt < 4; ++nt)
                acc[mt][nt] = __builtin_amdgcn_mfma_f32_16x16x32_bf16(
                    af[mt], bf[nt], acc[mt][nt], 0, 0, 0);
    }

#pragma unroll
    for (int mt = 0; mt < 4; ++mt) {
#pragma unroll
        for (int nt = 0; nt < 4; ++nt) {
            const int n = n0 + wn * 64 + nt * 16 + fr;
            const float bias = bu[n];
#pragma unroll
            for (int r = 0; r < 4; ++r) {
                const int m = m0 + wm * 64 + mt * 16 + (lane >> 4) * 4 + r;
                out[(size_t)m * E_ + n] = acc[mt][nt][r] + bias;
            }
        }
    }
}

// ---------------------------------------------------------------------------
// density sums over the context axis
// ---------------------------------------------------------------------------
__global__ __launch_bounds__(256) void dens_sum_kernel(
    const float* __restrict__ means, const float* __restrict__ sigmas,
    float* __restrict__ S)
{
    const int row = blockIdx.x * 256 + threadIdx.x;
    const int lane = threadIdx.x & 63;
    const int bh = row >> 11;

    const float* mrow = means + (size_t)row * 8;
    const float* srow = sigmas + (size_t)row * 8;
    const float4 ma = *(const float4*)(mrow);
    const float4 mb = *(const float4*)(mrow + 4);
    const float4 sa = *(const float4*)(srow);
    const float4 sb = *(const float4*)(srow + 4);
    const float mm[8] = {ma.x, ma.y, ma.z, ma.w, mb.x, mb.y, mb.z, mb.w};
    const float sg[8] = {sa.x, sa.y, sa.z, sa.w, sb.x, sb.y, sb.z, sb.w};

    int idx[16];
#pragma unroll
    for (int j = 0; j < 8; ++j) {
        int i0 = (int)floorf(mm[j]);
        i0 = min(max(i0, 0), C_ - 1);
        idx[2 * j] = i0;
        idx[2 * j + 1] = min(i0 + 1, C_ - 1);
    }
    unsigned dupm = 0;
#pragma unroll
    for (int p = 1; p < 16; ++p) {
        bool d = false;
#pragma unroll
        for (int q = 0; q < 15; ++q)
            if (q < p) d = d || (idx[q] == idx[p]);
        if (d) dupm |= (1u << p);
    }

#pragma unroll
    for (int p = 0; p < 16; ++p) {
        const float fi = (float)idx[p];
        const bool dup = (dupm >> p) & 1u;
#pragma unroll
        for (int kk = 0; kk < 8; ++kk) {
            const float t = (fi - mm[kk]) / sg[kk];
            float val = dup ? 0.0f : expf(-0.5f * t * t);
#pragma unroll
            for (int off = 1; off < 64; off <<= 1)
                val += __shfl_xor(val, off);
            if (lane == 0)
                atomicAdd(&S[bh * 128 + p * 8 + kk], val);
        }
    }
}

// ---------------------------------------------------------------------------
// attention core — LDS-free.  One wave per (b,h,c) row.
// Each wave owns its attentions row: nontemporal zero-stream, fence, then
// <=16 global atomicAdds into its own row (no cross-wave sharing).
// ---------------------------------------------------------------------------
__global__ __launch_bounds__(256) void attn_kernel(
    const float* __restrict__ means, const float* __restrict__ sigmas,
    const float* __restrict__ values, const float* __restrict__ S,
    const uint16_t* __restrict__ Qt, const uint16_t* __restrict__ Kt,
    const uint16_t* __restrict__ Vt, uint16_t* __restrict__ united,
    float* __restrict__ attn)
{
    const int w = threadIdx.x >> 6;
    const int lane = threadIdx.x & 63;
    const int row = blockIdx.x * 4 + w;
    const int bh = row >> 11;
    const int c = row & (C_ - 1);
    const int b = bh >> 3;
    const int h = bh & 7;

    const float* mrow = means + (size_t)row * 8;
    const float4 ma = *(const float4*)(mrow);
    const float4 mb = *(const float4*)(mrow + 4);
    const float mm[8] = {ma.x, ma.y, ma.z, ma.w, mb.x, mb.y, mb.z, mb.w};

    int idx[16];
#pragma unroll
    for (int j = 0; j < 8; ++j) {
        int i0 = (int)floorf(mm[j]);
        i0 = min(max(i0, 0), C_ - 1);
        idx[2 * j] = i0;
        idx[2 * j + 1] = min(i0 + 1, C_ - 1);
    }

    // ---- per-point weights on lanes 0..15 ----
    const int lp = lane & 15;
    int myidx = 0;
#pragma unroll
    for (int q = 0; q < 16; ++q)
        if (q == lp) myidx = idx[q];
    float wp = 0.0f;
    if (lane < 16) {
        bool dup = false;
#pragma unroll
        for (int q = 0; q < 15; ++q)
            dup = dup || ((q < lane) && (idx[q] == myidx));
        if (!dup) {
            const float* srow = sigmas + (size_t)row * 8;
            const float* vrow = values + (size_t)row * 8;
            const float4 sa = *(const float4*)(srow);
            const float4 sb = *(const float4*)(srow + 4);
            const float4 va = *(const float4*)(vrow);
            const float4 vb = *(const float4*)(vrow + 4);
            const float sg[8] = {sa.x, sa.y, sa.z, sa.w, sb.x, sb.y, sb.z, sb.w};
            const float vl[8] = {va.x, va.y, va.z, va.w, vb.x, vb.y, vb.z, vb.w};
            const float* Sp = S + bh * 128 + lane * 8;
            const float4 Sa = *(const float4*)(Sp);
            const float4 Sb = *(const float4*)(Sp + 4);
            const float Sv[8] = {Sa.x, Sa.y, Sa.z, Sa.w, Sb.x, Sb.y, Sb.z, Sb.w};
            const float fi = (float)myidx;
#pragma unroll
            for (int kk = 0; kk < 8; ++kk) {
                const float t = (fi - mm[kk]) / sg[kk];
                const float e = expf(-0.5f * t * t);
                wp = fmaf(vl[kk], e / (Sv[kk] + 1e-8f), wp);
            }
        }
    }

    // ---- dots in (p,g) layout: p = point, g covers dims [g*16, g*16+16) ----
    const int p = lane >> 2, g = lane & 3;
    int kidx = 0;
#pragma unroll
    for (int q = 0; q < 16; ++q)
        if (q == p) kidx = idx[q];

    const uint16_t* Qrow = Qt + ((size_t)row << 6);
    const uint16_t* Krow = Kt + ((((size_t)bh << 11) + kidx) << 6);
    const u16x8 qa = *(const u16x8*)(Qrow + g * 16);
    const u16x8 qb = *(const u16x8*)(Qrow + g * 16 + 8);
    const u16x8 ka = *(const u16x8*)(Krow + g * 16);
    const u16x8 kb = *(const u16x8*)(Krow + g * 16 + 8);
    float dot = 0.0f;
#pragma unroll
    for (int j = 0; j < 8; ++j) {
        dot = fmaf(bf2f(qa[j]), bf2f(ka[j]), dot);
        dot = fmaf(bf2f(qb[j]), bf2f(kb[j]), dot);
    }
    dot += __shfl_xor(dot, 1);
    dot += __shfl_xor(dot, 2);

    const float wvp = __shfl(wp, p);
    const float logit = wvp * dot;

    // softmax across the 16 p-groups
    float mx = logit;
#pragma unroll
    for (int off = 4; off < 64; off <<= 1)
        mx = fmaxf(mx, __shfl_xor(mx, off));
    const float e = expf(logit - mx);
    float se = e;
#pragma unroll
    for (int off = 4; off < 64; off <<= 1)
        se += __shfl_xor(se, off);
    const float sm = e / se;

    float smv[16];
#pragma unroll
    for (int q = 0; q < 16; ++q)
        smv[q] = __shfl(sm, q * 4);
    const float myw = __shfl(sm, lp * 4);   // dynamic-lane bpermute, no scratch

    // ---- V combine (lane = d) ----
    const uint16_t* Vbh = Vt + ((size_t)bh << 17);
    float acc = 0.0f;
#pragma unroll
    for (int q = 0; q < 16; ++q)
        acc = fmaf(bf2f(Vbh[((size_t)idx[q] << 6) + lane]), smv[q], acc);
    united[((size_t)(b * C_ + c)) * HD_ + h * 64 + lane] = f2bf(acc);

    // ---- attentions row: nontemporal zero-stream, fence, own-row atomics ----
    float* arow = attn + ((size_t)row << 11);
    const f32x4 z4 = {0.f, 0.f, 0.f, 0.f};
#pragma unroll
    for (int j = 0; j < 8; ++j)
        __builtin_nontemporal_store(z4, (f32x4*)&arow[(j * 64 + lane) * 4]);
    __threadfence();                        // own stores visible before own atomics
    if (lane < 16) atomicAdd(&arow[myidx], myw);
}

// ---------------------------------------------------------------------------
extern "C" void kernel_launch(void* const* d_in, const int* in_sizes, int n_in,
                              void* d_out, int out_size, void* d_ws,
                              size_t ws_size, hipStream_t stream) {
    const float* x      = (const float*)d_in[0];
    const float* means  = (const float*)d_in[2];
    const float* sigmas = (const float*)d_in[3];
    const float* values = (const float*)d_in[4];
    const float* Wk     = (const float*)d_in[5];
    const float* Wq     = (const float*)d_in[6];
    const float* Wv     = (const float*)d_in[7];
    const float* Wu     = (const float*)d_in[8];
    const float* bu     = (const float*)d_in[9];

    float* out  = (float*)d_out;
    float* attn = out + (size_t)M_ * E_;

    uint16_t* wsp = (uint16_t*)d_ws;
    uint16_t* xb     = wsp;                              // 4194304
    uint16_t* Wall   = xb + 4194304;                     // 1572864 (1536x1024)
    uint16_t* Wut    = Wall + 1572864;                   // 524288
    uint16_t* Qt     = Wut + 524288;                     // 2097152
    uint16_t* Kt     = Qt + 2097152;
    uint16_t* Vt     = Kt + 2097152;
    uint16_t* united = Vt + 2097152;                     // 2097152
    float*    S      = (float*)(united + 2097152);       // 2048 floats

    (void)hipMemsetAsync(S, 0, 2048 * sizeof(float), stream);

    convert_x_kernel<<<2048, 256, 0, stream>>>(x, xb);
    convert_wt_kernel<<<dim3(512, 1, 4), 256, 0, stream>>>(
        Wq, Wk, Wv, Wu, Wall, Wut);
    dens_sum_kernel<<<128, 256, 0, stream>>>(means, sigmas, S);
    gemm_qkv_kernel<<<dim3(12, 32), 256, 0, stream>>>(xb, Wall, Qt, Kt, Vt);
    attn_kernel<<<ROWS_ / 4, 256, 0, stream>>>(
        means, sigmas, values, S, Qt, Kt, Vt, united, attn);
    gemm_out_kernel<<<dim3(8, 32), 256, 0, stream>>>(united, Wut, bu, out);
}

// Round 5
// 423.350 us; speedup vs baseline: 3.4192x; 3.4192x over previous
//
#include <hip/hip_runtime.h>
#include <math.h>
#include <stdint.h>

#define B_ 2
#define H_ 8
#define C_ 2048
#define E_ 1024
#define D_ 64
#define KP_ 8
#define P_ 16
#define HD_ 512              // H*D
#define ROWS_ 32768          // B*H*C
#define M_ 4096              // B*C

typedef __bf16 bf16x8 __attribute__((ext_vector_type(8)));
typedef float f32x4 __attribute__((ext_vector_type(4)));
typedef uint16_t u16x8 __attribute__((ext_vector_type(8)));

__device__ inline uint16_t f2bf(float f) {
    union { float f; uint32_t u; } v; v.f = f;
    uint32_t u = v.u + 0x7FFF + ((v.u >> 16) & 1);   // RNE
    return (uint16_t)(u >> 16);
}
__device__ inline float bf2f(uint16_t h) {
    union { uint32_t u; float f; } v; v.u = ((uint32_t)h) << 16;
    return v.f;
}

// async global->LDS, 16B per lane; LDS dest = wave-uniform base + lane*16
__device__ inline void gload16(const uint16_t* g, uint16_t* l) {
    __builtin_amdgcn_global_load_lds(
        (const __attribute__((address_space(1))) void*)g,
        (__attribute__((address_space(3))) void*)l, 16, 0, 0);
}

// ---------------------------------------------------------------------------
// convert x (4096x1024 fp32) -> bf16
// ---------------------------------------------------------------------------
__global__ __launch_bounds__(256) void convert_x_kernel(
    const float* __restrict__ in, uint16_t* __restrict__ out)
{
    const int i = (blockIdx.x * 256 + threadIdx.x) * 8;
    const float4 a = *(const float4*)(in + i);
    const float4 b = *(const float4*)(in + i + 4);
    u16x8 o;
    o[0] = f2bf(a.x); o[1] = f2bf(a.y); o[2] = f2bf(a.z); o[3] = f2bf(a.w);
    o[4] = f2bf(b.x); o[5] = f2bf(b.y); o[6] = f2bf(b.z); o[7] = f2bf(b.w);
    *(u16x8*)(out + i) = o;
}

// ---------------------------------------------------------------------------
// transpose-convert weights.  z=0,1,2: Wq/Wk/Wv (1024x512) -> Wall rows
// [z*512, z*512+512) of a 1536x1024 bf16 matrix, Q/K scaled by 1/8 (exact).
// z=3: Wu (512x1024) -> Wut (1024x512).
// ---------------------------------------------------------------------------
__global__ __launch_bounds__(256) void convert_wt_kernel(
    const float* __restrict__ Wq, const float* __restrict__ Wk,
    const float* __restrict__ Wv, const float* __restrict__ Wu,
    uint16_t* __restrict__ Wall, uint16_t* __restrict__ Wut)
{
    const int z = blockIdx.z;
    const float* in; uint16_t* out; int R, Cc; float scale;
    if (z == 0)      { in = Wq; out = Wall;                 R = E_;  Cc = HD_; scale = 0.125f; }
    else if (z == 1) { in = Wk; out = Wall + 512 * 1024;    R = E_;  Cc = HD_; scale = 0.125f; }
    else if (z == 2) { in = Wv; out = Wall + 1024 * 1024;   R = E_;  Cc = HD_; scale = 1.0f; }
    else             { in = Wu; out = Wut;                  R = HD_; Cc = E_;  scale = 1.0f; }
    const int tiles_x = Cc >> 5;
    const int tx = blockIdx.x % tiles_x;
    const int ty = blockIdx.x / tiles_x;
    const int r0 = ty * 32, c0 = tx * 32;
    __shared__ float t[32][33];
    const int lx = threadIdx.x & 31, ly = threadIdx.x >> 5;
#pragma unroll
    for (int i = 0; i < 4; ++i)
        t[ly * 4 + i][lx] = in[(size_t)(r0 + ly * 4 + i) * Cc + c0 + lx];
    __syncthreads();
#pragma unroll
    for (int i = 0; i < 4; ++i)
        out[(size_t)(c0 + ly * 4 + i) * R + r0 + lx] = f2bf(t[lx][ly * 4 + i] * scale);
}

// ---------------------------------------------------------------------------
// Fused QKV GEMM (MFMA bf16): xb (4096x1024) @ Wall^T-rows (1536x1024)
// -> Q/K/V bf16 in (b,h,c,d) layout.  One dispatch, 384 blocks.
// ---------------------------------------------------------------------------
__global__ __launch_bounds__(256) void gemm_qkv_kernel(
    const uint16_t* __restrict__ xb, const uint16_t* __restrict__ Wall,
    uint16_t* __restrict__ Qt, uint16_t* __restrict__ Kt,
    uint16_t* __restrict__ Vt)
{
    const int K = E_;                       // 1024
    const int m0 = blockIdx.y * 128;
    const int n0 = blockIdx.x * 128;        // 0..1535
    const int z = n0 >> 9;
    uint16_t* __restrict__ Out = (z == 0) ? Qt : (z == 1) ? Kt : Vt;

    __shared__ __align__(16) uint16_t As[128 * 32];
    __shared__ __align__(16) uint16_t Bs[128 * 32];

    const int tid = threadIdx.x;
    const int w = tid >> 6, lane = tid & 63;
    const int wm = w & 1, wn = w >> 1;

    f32x4 acc[4][4] = {};

    const int r0s = (w * 2 + 0) * 16 + (lane >> 2);
    const int r1s = (w * 2 + 1) * 16 + (lane >> 2);
    const int ko  = (lane & 3) * 8;
    const uint16_t* gA0 = xb + (size_t)(m0 + r0s) * K + ko;
    const uint16_t* gA1 = xb + (size_t)(m0 + r1s) * K + ko;
    const uint16_t* gB0 = Wall + (size_t)(n0 + r0s) * K + ko;
    const uint16_t* gB1 = Wall + (size_t)(n0 + r1s) * K + ko;
    uint16_t* lA0 = &As[(w * 2 + 0) * 512];
    uint16_t* lA1 = &As[(w * 2 + 1) * 512];
    uint16_t* lB0 = &Bs[(w * 2 + 0) * 512];
    uint16_t* lB1 = &Bs[(w * 2 + 1) * 512];

    const int fr = lane & 15;
    const int fk = (lane >> 4) * 8;

    for (int k0 = 0; k0 < K; k0 += 32) {
        __syncthreads();
        gload16(gA0 + k0, lA0);
        gload16(gA1 + k0, lA1);
        gload16(gB0 + k0, lB0);
        gload16(gB1 + k0, lB1);
        __syncthreads();
        bf16x8 af[4], bf[4];
#pragma unroll
        for (int t = 0; t < 4; ++t) {
            af[t] = *(const bf16x8*)&As[(wm * 64 + t * 16 + fr) * 32 + fk];
            bf[t] = *(const bf16x8*)&Bs[(wn * 64 + t * 16 + fr) * 32 + fk];
        }
#pragma unroll
        for (int mt = 0; mt < 4; ++mt)
#pragma unroll
            for (int nt = 0; nt < 4; ++nt)
                acc[mt][nt] = __builtin_amdgcn_mfma_f32_16x16x32_bf16(
                    af[mt], bf[nt], acc[mt][nt], 0, 0, 0);
    }

#pragma unroll
    for (int mt = 0; mt < 4; ++mt) {
#pragma unroll
        for (int nt = 0; nt < 4; ++nt) {
            const int nl = (n0 & 511) + wn * 64 + nt * 16 + fr;
            const int h = nl >> 6, d = nl & 63;
#pragma unroll
            for (int r = 0; r < 4; ++r) {
                const int m = m0 + wm * 64 + mt * 16 + (lane >> 4) * 4 + r;
                const int b = m >> 11, c = m & (C_ - 1);
                Out[(((size_t)(b * H_ + h) * C_ + c) << 6) + d] =
                    f2bf(acc[mt][nt][r]);
            }
        }
    }
}

// ---------------------------------------------------------------------------
// GEMM 2 (MFMA bf16): united (4096x512) @ Wu^T-rows (1024x512) + bu
// ---------------------------------------------------------------------------
__global__ __launch_bounds__(256) void gemm_out_kernel(
    const uint16_t* __restrict__ U, const uint16_t* __restrict__ Wut,
    const float* __restrict__ bu, float* __restrict__ out)
{
    const int K = HD_;                      // 512
    const int m0 = blockIdx.y * 128;
    const int n0 = blockIdx.x * 128;        // N=1024

    __shared__ __align__(16) uint16_t As[128 * 32];
    __shared__ __align__(16) uint16_t Bs[128 * 32];

    const int tid = threadIdx.x;
    const int w = tid >> 6, lane = tid & 63;
    const int wm = w & 1, wn = w >> 1;

    f32x4 acc[4][4] = {};

    const int r0s = (w * 2 + 0) * 16 + (lane >> 2);
    const int r1s = (w * 2 + 1) * 16 + (lane >> 2);
    const int ko  = (lane & 3) * 8;
    const uint16_t* gA0 = U + (size_t)(m0 + r0s) * K + ko;
    const uint16_t* gA1 = U + (size_t)(m0 + r1s) * K + ko;
    const uint16_t* gB0 = Wut + (size_t)(n0 + r0s) * K + ko;
    const uint16_t* gB1 = Wut + (size_t)(n0 + r1s) * K + ko;
    uint16_t* lA0 = &As[(w * 2 + 0) * 512];
    uint16_t* lA1 = &As[(w * 2 + 1) * 512];
    uint16_t* lB0 = &Bs[(w * 2 + 0) * 512];
    uint16_t* lB1 = &Bs[(w * 2 + 1) * 512];

    const int fr = lane & 15;
    const int fk = (lane >> 4) * 8;

    for (int k0 = 0; k0 < K; k0 += 32) {
        __syncthreads();
        gload16(gA0 + k0, lA0);
        gload16(gA1 + k0, lA1);
        gload16(gB0 + k0, lB0);
        gload16(gB1 + k0, lB1);
        __syncthreads();
        bf16x8 af[4], bf[4];
#pragma unroll
        for (int t = 0; t < 4; ++t) {
            af[t] = *(const bf16x8*)&As[(wm * 64 + t * 16 + fr) * 32 + fk];
            bf[t] = *(const bf16x8*)&Bs[(wn * 64 + t * 16 + fr) * 32 + fk];
        }
#pragma unroll
        for (int mt = 0; mt < 4; ++mt)
#pragma unroll
            for (int nt = 0; nt < 4; ++nt)
                acc[mt][nt] = __builtin_amdgcn_mfma_f32_16x16x32_bf16(
                    af[mt], bf[nt], acc[mt][nt], 0, 0, 0);
    }

#pragma unroll
    for (int mt = 0; mt < 4; ++mt) {
#pragma unroll
        for (int nt = 0; nt < 4; ++nt) {
            const int n = n0 + wn * 64 + nt * 16 + fr;
            const float bias = bu[n];
#pragma unroll
            for (int r = 0; r < 4; ++r) {
                const int m = m0 + wm * 64 + mt * 16 + (lane >> 4) * 4 + r;
                out[(size_t)m * E_ + n] = acc[mt][nt][r] + bias;
            }
        }
    }
}

// ---------------------------------------------------------------------------
// density sums over the context axis
// ---------------------------------------------------------------------------
__global__ __launch_bounds__(256) void dens_sum_kernel(
    const float* __restrict__ means, const float* __restrict__ sigmas,
    float* __restrict__ S)
{
    const int row = blockIdx.x * 256 + threadIdx.x;
    const int lane = threadIdx.x & 63;
    const int bh = row >> 11;

    const float* mrow = means + (size_t)row * 8;
    const float* srow = sigmas + (size_t)row * 8;
    const float4 ma = *(const float4*)(mrow);
    const float4 mb = *(const float4*)(mrow + 4);
    const float4 sa = *(const float4*)(srow);
    const float4 sb = *(const float4*)(srow + 4);
    const float mm[8] = {ma.x, ma.y, ma.z, ma.w, mb.x, mb.y, mb.z, mb.w};
    const float sg[8] = {sa.x, sa.y, sa.z, sa.w, sb.x, sb.y, sb.z, sb.w};

    int idx[16];
#pragma unroll
    for (int j = 0; j < 8; ++j) {
        int i0 = (int)floorf(mm[j]);
        i0 = min(max(i0, 0), C_ - 1);
        idx[2 * j] = i0;
        idx[2 * j + 1] = min(i0 + 1, C_ - 1);
    }
    unsigned dupm = 0;
#pragma unroll
    for (int p = 1; p < 16; ++p) {
        bool d = false;
#pragma unroll
        for (int q = 0; q < 15; ++q)
            if (q < p) d = d || (idx[q] == idx[p]);
        if (d) dupm |= (1u << p);
    }

#pragma unroll
    for (int p = 0; p < 16; ++p) {
        const float fi = (float)idx[p];
        const bool dup = (dupm >> p) & 1u;
#pragma unroll
        for (int kk = 0; kk < 8; ++kk) {
            const float t = (fi - mm[kk]) / sg[kk];
            float val = dup ? 0.0f : expf(-0.5f * t * t);
#pragma unroll
            for (int off = 1; off < 64; off <<= 1)
                val += __shfl_xor(val, off);
            if (lane == 0)
                atomicAdd(&S[bh * 128 + p * 8 + kk], val);
        }
    }
}

// ---------------------------------------------------------------------------
// attention core.  One wave per (b,h,c) row; LDS row scatter (per-wave
// region, block barriers only), nontemporal final row stream.
// ---------------------------------------------------------------------------
__global__ __launch_bounds__(256) void attn_kernel(
    const float* __restrict__ means, const float* __restrict__ sigmas,
    const float* __restrict__ values, const float* __restrict__ S,
    const uint16_t* __restrict__ Qt, const uint16_t* __restrict__ Kt,
    const uint16_t* __restrict__ Vt, uint16_t* __restrict__ united,
    float* __restrict__ attn)
{
    __shared__ float rowbuf[4][2048];   // 32 KiB, per-wave 2048-float region
    const int w = threadIdx.x >> 6;
    const int lane = threadIdx.x & 63;
    const int row = blockIdx.x * 4 + w;
    const int bh = row >> 11;
    const int c = row & (C_ - 1);
    const int b = bh >> 3;
    const int h = bh & 7;

    const float* mrow = means + (size_t)row * 8;
    const float4 ma = *(const float4*)(mrow);
    const float4 mb = *(const float4*)(mrow + 4);
    const float mm[8] = {ma.x, ma.y, ma.z, ma.w, mb.x, mb.y, mb.z, mb.w};

    int idx[16];
#pragma unroll
    for (int j = 0; j < 8; ++j) {
        int i0 = (int)floorf(mm[j]);
        i0 = min(max(i0, 0), C_ - 1);
        idx[2 * j] = i0;
        idx[2 * j + 1] = min(i0 + 1, C_ - 1);
    }

    // ---- per-point weights on lanes 0..15 ----
    const int lp = lane & 15;
    int myidx = 0;
#pragma unroll
    for (int q = 0; q < 16; ++q)
        if (q == lp) myidx = idx[q];
    float wp = 0.0f;
    if (lane < 16) {
        bool dup = false;
#pragma unroll
        for (int q = 0; q < 15; ++q)
            dup = dup || ((q < lane) && (idx[q] == myidx));
        if (!dup) {
            const float* srow = sigmas + (size_t)row * 8;
            const float* vrow = values + (size_t)row * 8;
            const float4 sa = *(const float4*)(srow);
            const float4 sb = *(const float4*)(srow + 4);
            const float4 va = *(const float4*)(vrow);
            const float4 vb = *(const float4*)(vrow + 4);
            const float sg[8] = {sa.x, sa.y, sa.z, sa.w, sb.x, sb.y, sb.z, sb.w};
            const float vl[8] = {va.x, va.y, va.z, va.w, vb.x, vb.y, vb.z, vb.w};
            const float* Sp = S + bh * 128 + lane * 8;
            const float4 Sa = *(const float4*)(Sp);
            const float4 Sb = *(const float4*)(Sp + 4);
            const float Sv[8] = {Sa.x, Sa.y, Sa.z, Sa.w, Sb.x, Sb.y, Sb.z, Sb.w};
            const float fi = (float)myidx;
#pragma unroll
            for (int kk = 0; kk < 8; ++kk) {
                const float t = (fi - mm[kk]) / sg[kk];
                const float e = expf(-0.5f * t * t);
                wp = fmaf(vl[kk], e / (Sv[kk] + 1e-8f), wp);
            }
        }
    }

    // ---- dots in (p,g) layout: p = point, g covers dims [g*16, g*16+16) ----
    const int p = lane >> 2, g = lane & 3;
    int kidx = 0;
#pragma unroll
    for (int q = 0; q < 16; ++q)
        if (q == p) kidx = idx[q];

    const uint16_t* Qrow = Qt + ((size_t)row << 6);
    const uint16_t* Krow = Kt + ((((size_t)bh << 11) + kidx) << 6);
    const u16x8 qa = *(const u16x8*)(Qrow + g * 16);
    const u16x8 qb = *(const u16x8*)(Qrow + g * 16 + 8);
    const u16x8 ka = *(const u16x8*)(Krow + g * 16);
    const u16x8 kb = *(const u16x8*)(Krow + g * 16 + 8);
    float dot = 0.0f;
#pragma unroll
    for (int j = 0; j < 8; ++j) {
        dot = fmaf(bf2f(qa[j]), bf2f(ka[j]), dot);
        dot = fmaf(bf2f(qb[j]), bf2f(kb[j]), dot);
    }
    dot += __shfl_xor(dot, 1);
    dot += __shfl_xor(dot, 2);

    const float wvp = __shfl(wp, p);
    const float logit = wvp * dot;

    // softmax across the 16 p-groups
    float mx = logit;
#pragma unroll
    for (int off = 4; off < 64; off <<= 1)
        mx = fmaxf(mx, __shfl_xor(mx, off));
    const float e = expf(logit - mx);
    float se = e;
#pragma unroll
    for (int off = 4; off < 64; off <<= 1)
        se += __shfl_xor(se, off);
    const float sm = e / se;

    float smv[16];
#pragma unroll
    for (int q = 0; q < 16; ++q)
        smv[q] = __shfl(sm, q * 4);
    const float myw = __shfl(sm, lp * 4);

    // ---- V combine (lane = d) ----
    const uint16_t* Vbh = Vt + ((size_t)bh << 17);
    float acc = 0.0f;
#pragma unroll
    for (int q = 0; q < 16; ++q)
        acc = fmaf(bf2f(Vbh[((size_t)idx[q] << 6) + lane]), smv[q], acc);
    united[((size_t)(b * C_ + c)) * HD_ + h * 64 + lane] = f2bf(acc);

    // ---- attentions row: zero LDS, scatter-add, nontemporal stream out ----
    const f32x4 z4 = {0.f, 0.f, 0.f, 0.f};
#pragma unroll
    for (int j = 0; j < 8; ++j)
        *(f32x4*)&rowbuf[w][(j * 64 + lane) * 4] = z4;
    __syncthreads();
    if (lane < 16) atomicAdd(&rowbuf[w][myidx], myw);
    __syncthreads();
    float* arow = attn + ((size_t)row << 11);
#pragma unroll
    for (int j = 0; j < 8; ++j) {
        const int o = (j * 64 + lane) * 4;
        __builtin_nontemporal_store(*(const f32x4*)&rowbuf[w][o], (f32x4*)&arow[o]);
    }
}

// ---------------------------------------------------------------------------
extern "C" void kernel_launch(void* const* d_in, const int* in_sizes, int n_in,
                              void* d_out, int out_size, void* d_ws,
                              size_t ws_size, hipStream_t stream) {
    const float* x      = (const float*)d_in[0];
    const float* means  = (const float*)d_in[2];
    const float* sigmas = (const float*)d_in[3];
    const float* values = (const float*)d_in[4];
    const float* Wk     = (const float*)d_in[5];
    const float* Wq     = (const float*)d_in[6];
    const float* Wv     = (const float*)d_in[7];
    const float* Wu     = (const float*)d_in[8];
    const float* bu     = (const float*)d_in[9];

    float* out  = (float*)d_out;
    float* attn = out + (size_t)M_ * E_;

    uint16_t* wsp = (uint16_t*)d_ws;
    uint16_t* xb     = wsp;                              // 4194304
    uint16_t* Wall   = xb + 4194304;                     // 1572864 (1536x1024)
    uint16_t* Wut    = Wall + 1572864;                   // 524288
    uint16_t* Qt     = Wut + 524288;                     // 2097152
    uint16_t* Kt     = Qt + 2097152;
    uint16_t* Vt     = Kt + 2097152;
    uint16_t* united = Vt + 2097152;                     // 2097152
    float*    S      = (float*)(united + 2097152);       // 2048 floats

    (void)hipMemsetAsync(S, 0, 2048 * sizeof(float), stream);

    convert_x_kernel<<<2048, 256, 0, stream>>>(x, xb);
    convert_wt_kernel<<<dim3(512, 1, 4), 256, 0, stream>>>(
        Wq, Wk, Wv, Wu, Wall, Wut);
    dens_sum_kernel<<<128, 256, 0, stream>>>(means, sigmas, S);
    gemm_qkv_kernel<<<dim3(12, 32), 256, 0, stream>>>(xb, Wall, Qt, Kt, Vt);
    attn_kernel<<<ROWS_ / 4, 256, 0, stream>>>(
        means, sigmas, values, S, Qt, Kt, Vt, united, attn);
    gemm_out_kernel<<<dim3(8, 32), 256, 0, stream>>>(united, Wut, bu, out);
}

// Round 6
// 417.010 us; speedup vs baseline: 3.4712x; 1.0152x over previous
//
#include <hip/hip_runtime.h>
#include <math.h>
#include <stdint.h>

#define B_ 2
#define H_ 8
#define C_ 2048
#define E_ 1024
#define D_ 64
#define KP_ 8
#define P_ 16
#define HD_ 512              // H*D
#define ROWS_ 32768          // B*H*C
#define M_ 4096              // B*C

typedef __bf16 bf16x8 __attribute__((ext_vector_type(8)));
typedef float f32x4 __attribute__((ext_vector_type(4)));
typedef uint16_t u16x8 __attribute__((ext_vector_type(8)));

__device__ inline uint16_t f2bf(float f) {
    union { float f; uint32_t u; } v; v.f = f;
    uint32_t u = v.u + 0x7FFF + ((v.u >> 16) & 1);   // RNE
    return (uint16_t)(u >> 16);
}
__device__ inline float bf2f(uint16_t h) {
    union { uint32_t u; float f; } v; v.u = ((uint32_t)h) << 16;
    return v.f;
}

// async global->LDS, 16B per lane; LDS dest = wave-uniform base + lane*16
__device__ inline void gload16(const uint16_t* g, uint16_t* l) {
    __builtin_amdgcn_global_load_lds(
        (const __attribute__((address_space(1))) void*)g,
        (__attribute__((address_space(3))) void*)l, 16, 0, 0);
}

// ---------------------------------------------------------------------------
// prep kernel: one dispatch for x-convert, weight transpose-convert, and
// density context-sums.
//   blocks [0, 2048)      : convert x (fp32 -> bf16), 8 elem/thread
//   blocks [2048, 4096)   : transpose-convert one 32x32 weight tile
//   blocks [4096, 4224)   : density sums (one thread per (b,h,c) row)
// ---------------------------------------------------------------------------
__global__ __launch_bounds__(256) void prep_kernel(
    const float* __restrict__ x,
    const float* __restrict__ Wq, const float* __restrict__ Wk,
    const float* __restrict__ Wv, const float* __restrict__ Wu,
    const float* __restrict__ means, const float* __restrict__ sigmas,
    uint16_t* __restrict__ xb, uint16_t* __restrict__ Wall,
    uint16_t* __restrict__ Wut, float* __restrict__ S)
{
    const int bx = blockIdx.x;
    if (bx < 2048) {
        const int i = (bx * 256 + threadIdx.x) * 8;
        const float4 a = *(const float4*)(x + i);
        const float4 b = *(const float4*)(x + i + 4);
        u16x8 o;
        o[0] = f2bf(a.x); o[1] = f2bf(a.y); o[2] = f2bf(a.z); o[3] = f2bf(a.w);
        o[4] = f2bf(b.x); o[5] = f2bf(b.y); o[6] = f2bf(b.z); o[7] = f2bf(b.w);
        *(u16x8*)(xb + i) = o;
        return;
    }
    if (bx < 4096) {
        const int t = bx - 2048;          // 0..2047; z = t>>9, tile = t&511
        const int z = t >> 9;
        const float* in; uint16_t* out; int R, Cc; float scale;
        if (z == 0)      { in = Wq; out = Wall;               R = E_;  Cc = HD_; scale = 0.125f; }
        else if (z == 1) { in = Wk; out = Wall + 512 * 1024;  R = E_;  Cc = HD_; scale = 0.125f; }
        else if (z == 2) { in = Wv; out = Wall + 1024 * 1024; R = E_;  Cc = HD_; scale = 1.0f; }
        else             { in = Wu; out = Wut;                R = HD_; Cc = E_;  scale = 1.0f; }
        const int tiles_x = Cc >> 5;
        const int ti = t & 511;
        const int tx = ti % tiles_x;
        const int ty = ti / tiles_x;
        const int r0 = ty * 32, c0 = tx * 32;
        __shared__ float tbuf[32][33];
        const int lx = threadIdx.x & 31, ly = threadIdx.x >> 5;
#pragma unroll
        for (int i = 0; i < 4; ++i)
            tbuf[ly * 4 + i][lx] = in[(size_t)(r0 + ly * 4 + i) * Cc + c0 + lx];
        __syncthreads();
#pragma unroll
        for (int i = 0; i < 4; ++i)
            out[(size_t)(c0 + ly * 4 + i) * R + r0 + lx] =
                f2bf(tbuf[lx][ly * 4 + i] * scale);
        return;
    }
    // ---- density sums ----
    const int row = (bx - 4096) * 256 + threadIdx.x;   // 0..32767
    const int lane = threadIdx.x & 63;
    const int bh = row >> 11;

    const float* mrow = means + (size_t)row * 8;
    const float* srow = sigmas + (size_t)row * 8;
    const float4 ma = *(const float4*)(mrow);
    const float4 mb = *(const float4*)(mrow + 4);
    const float4 sa = *(const float4*)(srow);
    const float4 sb = *(const float4*)(srow + 4);
    const float mm[8] = {ma.x, ma.y, ma.z, ma.w, mb.x, mb.y, mb.z, mb.w};
    const float sg[8] = {sa.x, sa.y, sa.z, sa.w, sb.x, sb.y, sb.z, sb.w};

    int idx[16];
#pragma unroll
    for (int j = 0; j < 8; ++j) {
        int i0 = (int)floorf(mm[j]);
        i0 = min(max(i0, 0), C_ - 1);
        idx[2 * j] = i0;
        idx[2 * j + 1] = min(i0 + 1, C_ - 1);
    }
    unsigned dupm = 0;
#pragma unroll
    for (int p = 1; p < 16; ++p) {
        bool d = false;
#pragma unroll
        for (int q = 0; q < 15; ++q)
            if (q < p) d = d || (idx[q] == idx[p]);
        if (d) dupm |= (1u << p);
    }
#pragma unroll
    for (int p = 0; p < 16; ++p) {
        const float fi = (float)idx[p];
        const bool dup = (dupm >> p) & 1u;
#pragma unroll
        for (int kk = 0; kk < 8; ++kk) {
            const float t = (fi - mm[kk]) / sg[kk];
            float val = dup ? 0.0f : expf(-0.5f * t * t);
#pragma unroll
            for (int off = 1; off < 64; off <<= 1)
                val += __shfl_xor(val, off);
            if (lane == 0)
                atomicAdd(&S[bh * 128 + p * 8 + kk], val);
        }
    }
}

// ---------------------------------------------------------------------------
// Fused QKV GEMM (MFMA bf16): xb (4096x1024) @ Wall^T-rows (1536x1024)
// -> Q/K/V bf16 in (b,h,c,d) layout.  LDS-staged coalesced epilogue:
// tile re-staged in LDS (row stride 136), streamed as u16x8 per lane into
// two contiguous 16 KB per-head regions.
// ---------------------------------------------------------------------------
__global__ __launch_bounds__(256) void gemm_qkv_kernel(
    const uint16_t* __restrict__ xb, const uint16_t* __restrict__ Wall,
    uint16_t* __restrict__ Qt, uint16_t* __restrict__ Kt,
    uint16_t* __restrict__ Vt)
{
    const int K = E_;                       // 1024
    const int m0 = blockIdx.y * 128;
    const int n0 = blockIdx.x * 128;        // 0..1535
    const int z = n0 >> 9;
    uint16_t* __restrict__ Out = (z == 0) ? Qt : (z == 1) ? Kt : Vt;

    // As = smem[0..4096), Bs = smem[4096..8192); epilogue tile = smem[0..17408)
    __shared__ __align__(16) uint16_t smem[128 * 136];
    uint16_t* As = smem;
    uint16_t* Bs = smem + 4096;

    const int tid = threadIdx.x;
    const int w = tid >> 6, lane = tid & 63;
    const int wm = w & 1, wn = w >> 1;

    f32x4 acc[4][4] = {};

    const int r0s = (w * 2 + 0) * 16 + (lane >> 2);
    const int r1s = (w * 2 + 1) * 16 + (lane >> 2);
    const int ko  = (lane & 3) * 8;
    const uint16_t* gA0 = xb + (size_t)(m0 + r0s) * K + ko;
    const uint16_t* gA1 = xb + (size_t)(m0 + r1s) * K + ko;
    const uint16_t* gB0 = Wall + (size_t)(n0 + r0s) * K + ko;
    const uint16_t* gB1 = Wall + (size_t)(n0 + r1s) * K + ko;
    uint16_t* lA0 = &As[(w * 2 + 0) * 512];
    uint16_t* lA1 = &As[(w * 2 + 1) * 512];
    uint16_t* lB0 = &Bs[(w * 2 + 0) * 512];
    uint16_t* lB1 = &Bs[(w * 2 + 1) * 512];

    const int fr = lane & 15;
    const int fk = (lane >> 4) * 8;

    for (int k0 = 0; k0 < K; k0 += 32) {
        __syncthreads();
        gload16(gA0 + k0, lA0);
        gload16(gA1 + k0, lA1);
        gload16(gB0 + k0, lB0);
        gload16(gB1 + k0, lB1);
        __syncthreads();
        bf16x8 af[4], bf[4];
#pragma unroll
        for (int t = 0; t < 4; ++t) {
            af[t] = *(const bf16x8*)&As[(wm * 64 + t * 16 + fr) * 32 + fk];
            bf[t] = *(const bf16x8*)&Bs[(wn * 64 + t * 16 + fr) * 32 + fk];
        }
#pragma unroll
        for (int mt = 0; mt < 4; ++mt)
#pragma unroll
            for (int nt = 0; nt < 4; ++nt)
                acc[mt][nt] = __builtin_amdgcn_mfma_f32_16x16x32_bf16(
                    af[mt], bf[nt], acc[mt][nt], 0, 0, 0);
    }

    // ---- epilogue: stage bf16 tile in LDS, stream coalesced ----
    __syncthreads();                        // K-loop LDS readers done
#pragma unroll
    for (int mt = 0; mt < 4; ++mt)
#pragma unroll
        for (int nt = 0; nt < 4; ++nt) {
            const int col = wn * 64 + nt * 16 + fr;
#pragma unroll
            for (int r = 0; r < 4; ++r) {
                const int rw = wm * 64 + mt * 16 + (lane >> 4) * 4 + r;
                smem[rw * 136 + col] = f2bf(acc[mt][nt][r]);
            }
        }
    __syncthreads();
#pragma unroll
    for (int it = 0; it < 8; ++it) {
        const int e0 = (it * 256 + tid) * 8;
        const int row = e0 >> 7, tcol = e0 & 127;
        const int nl = (n0 & 511) + tcol;
        const int h = nl >> 6, d = nl & 63;
        const int m = m0 + row;
        const int b = m >> 11, c = m & (C_ - 1);
        *(u16x8*)&Out[(((size_t)(b * H_ + h) * C_ + c) << 6) + d] =
            *(const u16x8*)&smem[row * 136 + tcol];
    }
}

// ---------------------------------------------------------------------------
// GEMM 2 (MFMA bf16): united (4096x512) @ Wu^T-rows (1024x512) + bu
// ---------------------------------------------------------------------------
__global__ __launch_bounds__(256) void gemm_out_kernel(
    const uint16_t* __restrict__ U, const uint16_t* __restrict__ Wut,
    const float* __restrict__ bu, float* __restrict__ out)
{
    const int K = HD_;                      // 512
    const int m0 = blockIdx.y * 128;
    const int n0 = blockIdx.x * 128;        // N=1024

    __shared__ __align__(16) uint16_t As[128 * 32];
    __shared__ __align__(16) uint16_t Bs[128 * 32];

    const int tid = threadIdx.x;
    const int w = tid >> 6, lane = tid & 63;
    const int wm = w & 1, wn = w >> 1;

    f32x4 acc[4][4] = {};

    const int r0s = (w * 2 + 0) * 16 + (lane >> 2);
    const int r1s = (w * 2 + 1) * 16 + (lane >> 2);
    const int ko  = (lane & 3) * 8;
    const uint16_t* gA0 = U + (size_t)(m0 + r0s) * K + ko;
    const uint16_t* gA1 = U + (size_t)(m0 + r1s) * K + ko;
    const uint16_t* gB0 = Wut + (size_t)(n0 + r0s) * K + ko;
    const uint16_t* gB1 = Wut + (size_t)(n0 + r1s) * K + ko;
    uint16_t* lA0 = &As[(w * 2 + 0) * 512];
    uint16_t* lA1 = &As[(w * 2 + 1) * 512];
    uint16_t* lB0 = &Bs[(w * 2 + 0) * 512];
    uint16_t* lB1 = &Bs[(w * 2 + 1) * 512];

    const int fr = lane & 15;
    const int fk = (lane >> 4) * 8;

    for (int k0 = 0; k0 < K; k0 += 32) {
        __syncthreads();
        gload16(gA0 + k0, lA0);
        gload16(gA1 + k0, lA1);
        gload16(gB0 + k0, lB0);
        gload16(gB1 + k0, lB1);
        __syncthreads();
        bf16x8 af[4], bf[4];
#pragma unroll
        for (int t = 0; t < 4; ++t) {
            af[t] = *(const bf16x8*)&As[(wm * 64 + t * 16 + fr) * 32 + fk];
            bf[t] = *(const bf16x8*)&Bs[(wn * 64 + t * 16 + fr) * 32 + fk];
        }
#pragma unroll
        for (int mt = 0; mt < 4; ++mt)
#pragma unroll
            for (int nt = 0; nt < 4; ++nt)
                acc[mt][nt] = __builtin_amdgcn_mfma_f32_16x16x32_bf16(
                    af[mt], bf[nt], acc[mt][nt], 0, 0, 0);
    }

#pragma unroll
    for (int mt = 0; mt < 4; ++mt) {
#pragma unroll
        for (int nt = 0; nt < 4; ++nt) {
            const int n = n0 + wn * 64 + nt * 16 + fr;
            const float bias = bu[n];
#pragma unroll
            for (int r = 0; r < 4; ++r) {
                const int m = m0 + wm * 64 + mt * 16 + (lane >> 4) * 4 + r;
                out[(size_t)m * E_ + n] = acc[mt][nt][r] + bias;
            }
        }
    }
}

// ---------------------------------------------------------------------------
// attention core.  One wave per (b,h,c) row; LDS row scatter (per-wave
// region, block barriers only), nontemporal final row stream.
// ---------------------------------------------------------------------------
__global__ __launch_bounds__(256) void attn_kernel(
    const float* __restrict__ means, const float* __restrict__ sigmas,
    const float* __restrict__ values, const float* __restrict__ S,
    const uint16_t* __restrict__ Qt, const uint16_t* __restrict__ Kt,
    const uint16_t* __restrict__ Vt, uint16_t* __restrict__ united,
    float* __restrict__ attn)
{
    __shared__ float rowbuf[4][2048];   // 32 KiB, per-wave 2048-float region
    const int w = threadIdx.x >> 6;
    const int lane = threadIdx.x & 63;
    const int row = blockIdx.x * 4 + w;
    const int bh = row >> 11;
    const int c = row & (C_ - 1);
    const int b = bh >> 3;
    const int h = bh & 7;

    const float* mrow = means + (size_t)row * 8;
    const float4 ma = *(const float4*)(mrow);
    const float4 mb = *(const float4*)(mrow + 4);
    const float mm[8] = {ma.x, ma.y, ma.z, ma.w, mb.x, mb.y, mb.z, mb.w};

    int idx[16];
#pragma unroll
    for (int j = 0; j < 8; ++j) {
        int i0 = (int)floorf(mm[j]);
        i0 = min(max(i0, 0), C_ - 1);
        idx[2 * j] = i0;
        idx[2 * j + 1] = min(i0 + 1, C_ - 1);
    }

    // ---- per-point weights on lanes 0..15 ----
    const int lp = lane & 15;
    int myidx = 0;
#pragma unroll
    for (int q = 0; q < 16; ++q)
        if (q == lp) myidx = idx[q];
    float wp = 0.0f;
    if (lane < 16) {
        bool dup = false;
#pragma unroll
        for (int q = 0; q < 15; ++q)
            dup = dup || ((q < lane) && (idx[q] == myidx));
        if (!dup) {
            const float* srow = sigmas + (size_t)row * 8;
            const float* vrow = values + (size_t)row * 8;
            const float4 sa = *(const float4*)(srow);
            const float4 sb = *(const float4*)(srow + 4);
            const float4 va = *(const float4*)(vrow);
            const float4 vb = *(const float4*)(vrow + 4);
            const float sg[8] = {sa.x, sa.y, sa.z, sa.w, sb.x, sb.y, sb.z, sb.w};
            const float vl[8] = {va.x, va.y, va.z, va.w, vb.x, vb.y, vb.z, vb.w};
            const float* Sp = S + bh * 128 + lane * 8;
            const float4 Sa = *(const float4*)(Sp);
            const float4 Sb = *(const float4*)(Sp + 4);
            const float Sv[8] = {Sa.x, Sa.y, Sa.z, Sa.w, Sb.x, Sb.y, Sb.z, Sb.w};
            const float fi = (float)myidx;
#pragma unroll
            for (int kk = 0; kk < 8; ++kk) {
                const float t = (fi - mm[kk]) / sg[kk];
                const float e = expf(-0.5f * t * t);
                wp = fmaf(vl[kk], e / (Sv[kk] + 1e-8f), wp);
            }
        }
    }

    // ---- dots in (p,g) layout: p = point, g covers dims [g*16, g*16+16) ----
    const int p = lane >> 2, g = lane & 3;
    int kidx = 0;
#pragma unroll
    for (int q = 0; q < 16; ++q)
        if (q == p) kidx = idx[q];

    const uint16_t* Qrow = Qt + ((size_t)row << 6);
    const uint16_t* Krow = Kt + ((((size_t)bh << 11) + kidx) << 6);
    const u16x8 qa = *(const u16x8*)(Qrow + g * 16);
    const u16x8 qb = *(const u16x8*)(Qrow + g * 16 + 8);
    const u16x8 ka = *(const u16x8*)(Krow + g * 16);
    const u16x8 kb = *(const u16x8*)(Krow + g * 16 + 8);
    float dot = 0.0f;
#pragma unroll
    for (int j = 0; j < 8; ++j) {
        dot = fmaf(bf2f(qa[j]), bf2f(ka[j]), dot);
        dot = fmaf(bf2f(qb[j]), bf2f(kb[j]), dot);
    }
    dot += __shfl_xor(dot, 1);
    dot += __shfl_xor(dot, 2);

    const float wvp = __shfl(wp, p);
    const float logit = wvp * dot;

    // softmax across the 16 p-groups
    float mx = logit;
#pragma unroll
    for (int off = 4; off < 64; off <<= 1)
        mx = fmaxf(mx, __shfl_xor(mx, off));
    const float e = expf(logit - mx);
    float se = e;
#pragma unroll
    for (int off = 4; off < 64; off <<= 1)
        se += __shfl_xor(se, off);
    const float sm = e / se;

    float smv[16];
#pragma unroll
    for (int q = 0; q < 16; ++q)
        smv[q] = __shfl(sm, q * 4);
    const float myw = __shfl(sm, lp * 4);

    // ---- V combine (lane = d) ----
    const uint16_t* Vbh = Vt + ((size_t)bh << 17);
    float acc = 0.0f;
#pragma unroll
    for (int q = 0; q < 16; ++q)
        acc = fmaf(bf2f(Vbh[((size_t)idx[q] << 6) + lane]), smv[q], acc);
    united[((size_t)(b * C_ + c)) * HD_ + h * 64 + lane] = f2bf(acc);

    // ---- attentions row: zero LDS, scatter-add, nontemporal stream out ----
    const f32x4 z4 = {0.f, 0.f, 0.f, 0.f};
#pragma unroll
    for (int j = 0; j < 8; ++j)
        *(f32x4*)&rowbuf[w][(j * 64 + lane) * 4] = z4;
    __syncthreads();
    if (lane < 16) atomicAdd(&rowbuf[w][myidx], myw);
    __syncthreads();
    float* arow = attn + ((size_t)row << 11);
#pragma unroll
    for (int j = 0; j < 8; ++j) {
        const int o = (j * 64 + lane) * 4;
        __builtin_nontemporal_store(*(const f32x4*)&rowbuf[w][o], (f32x4*)&arow[o]);
    }
}

// ---------------------------------------------------------------------------
extern "C" void kernel_launch(void* const* d_in, const int* in_sizes, int n_in,
                              void* d_out, int out_size, void* d_ws,
                              size_t ws_size, hipStream_t stream) {
    const float* x      = (const float*)d_in[0];
    const float* means  = (const float*)d_in[2];
    const float* sigmas = (const float*)d_in[3];
    const float* values = (const float*)d_in[4];
    const float* Wk     = (const float*)d_in[5];
    const float* Wq     = (const float*)d_in[6];
    const float* Wv     = (const float*)d_in[7];
    const float* Wu     = (const float*)d_in[8];
    const float* bu     = (const float*)d_in[9];

    float* out  = (float*)d_out;
    float* attn = out + (size_t)M_ * E_;

    uint16_t* wsp = (uint16_t*)d_ws;
    uint16_t* xb     = wsp;                              // 4194304
    uint16_t* Wall   = xb + 4194304;                     // 1572864 (1536x1024)
    uint16_t* Wut    = Wall + 1572864;                   // 524288
    uint16_t* Qt     = Wut + 524288;                     // 2097152
    uint16_t* Kt     = Qt + 2097152;
    uint16_t* Vt     = Kt + 2097152;
    uint16_t* united = Vt + 2097152;                     // 2097152
    float*    S      = (float*)(united + 2097152);       // 2048 floats

    (void)hipMemsetAsync(S, 0, 2048 * sizeof(float), stream);

    prep_kernel<<<4224, 256, 0, stream>>>(
        x, Wq, Wk, Wv, Wu, means, sigmas, xb, Wall, Wut, S);
    gemm_qkv_kernel<<<dim3(12, 32), 256, 0, stream>>>(xb, Wall, Qt, Kt, Vt);
    attn_kernel<<<ROWS_ / 4, 256, 0, stream>>>(
        means, sigmas, values, S, Qt, Kt, Vt, united, attn);
    gemm_out_kernel<<<dim3(8, 32), 256, 0, stream>>>(united, Wut, bu, out);
}

// Round 7
// 413.127 us; speedup vs baseline: 3.5038x; 1.0094x over previous
//
#include <hip/hip_runtime.h>
#include <math.h>
#include <stdint.h>

#define B_ 2
#define H_ 8
#define C_ 2048
#define E_ 1024
#define D_ 64
#define KP_ 8
#define P_ 16
#define HD_ 512              // H*D
#define ROWS_ 32768          // B*H*C
#define M_ 4096              // B*C

typedef __bf16 bf16x8 __attribute__((ext_vector_type(8)));
typedef float f32x4 __attribute__((ext_vector_type(4)));
typedef uint16_t u16x8 __attribute__((ext_vector_type(8)));

__device__ inline uint16_t f2bf(float f) {
    union { float f; uint32_t u; } v; v.f = f;
    uint32_t u = v.u + 0x7FFF + ((v.u >> 16) & 1);   // RNE
    return (uint16_t)(u >> 16);
}
__device__ inline float bf2f(uint16_t h) {
    union { uint32_t u; float f; } v; v.u = ((uint32_t)h) << 16;
    return v.f;
}

// async global->LDS, 16B per lane; LDS dest = wave-uniform base + lane*16
__device__ inline void gload16(const uint16_t* g, uint16_t* l) {
    __builtin_amdgcn_global_load_lds(
        (const __attribute__((address_space(1))) void*)g,
        (__attribute__((address_space(3))) void*)l, 16, 0, 0);
}

// ---------------------------------------------------------------------------
// prep kernel: x-convert, weight transpose-convert, density context-sums.
//   blocks [0, 2048)      : convert x (fp32 -> bf16), 8 elem/thread
//   blocks [2048, 4096)   : transpose-convert one 32x32 weight tile
//   blocks [4096, 4224)   : density sums (one thread per (b,h,c) row)
// ---------------------------------------------------------------------------
__global__ __launch_bounds__(256) void prep_kernel(
    const float* __restrict__ x,
    const float* __restrict__ Wq, const float* __restrict__ Wk,
    const float* __restrict__ Wv, const float* __restrict__ Wu,
    const float* __restrict__ means, const float* __restrict__ sigmas,
    uint16_t* __restrict__ xb, uint16_t* __restrict__ Wall,
    uint16_t* __restrict__ Wut, float* __restrict__ S)
{
    const int bx = blockIdx.x;
    if (bx < 2048) {
        const int i = (bx * 256 + threadIdx.x) * 8;
        const float4 a = *(const float4*)(x + i);
        const float4 b = *(const float4*)(x + i + 4);
        u16x8 o;
        o[0] = f2bf(a.x); o[1] = f2bf(a.y); o[2] = f2bf(a.z); o[3] = f2bf(a.w);
        o[4] = f2bf(b.x); o[5] = f2bf(b.y); o[6] = f2bf(b.z); o[7] = f2bf(b.w);
        *(u16x8*)(xb + i) = o;
        return;
    }
    if (bx < 4096) {
        const int t = bx - 2048;
        const int z = t >> 9;
        const float* in; uint16_t* out; int R, Cc; float scale;
        if (z == 0)      { in = Wq; out = Wall;               R = E_;  Cc = HD_; scale = 0.125f; }
        else if (z == 1) { in = Wk; out = Wall + 512 * 1024;  R = E_;  Cc = HD_; scale = 0.125f; }
        else if (z == 2) { in = Wv; out = Wall + 1024 * 1024; R = E_;  Cc = HD_; scale = 1.0f; }
        else             { in = Wu; out = Wut;                R = HD_; Cc = E_;  scale = 1.0f; }
        const int tiles_x = Cc >> 5;
        const int ti = t & 511;
        const int tx = ti % tiles_x;
        const int ty = ti / tiles_x;
        const int r0 = ty * 32, c0 = tx * 32;
        __shared__ float tbuf[32][33];
        const int lx = threadIdx.x & 31, ly = threadIdx.x >> 5;
#pragma unroll
        for (int i = 0; i < 4; ++i)
            tbuf[ly * 4 + i][lx] = in[(size_t)(r0 + ly * 4 + i) * Cc + c0 + lx];
        __syncthreads();
#pragma unroll
        for (int i = 0; i < 4; ++i)
            out[(size_t)(c0 + ly * 4 + i) * R + r0 + lx] =
                f2bf(tbuf[lx][ly * 4 + i] * scale);
        return;
    }
    // ---- density sums ----
    const int row = (bx - 4096) * 256 + threadIdx.x;
    const int lane = threadIdx.x & 63;
    const int bh = row >> 11;

    const float* mrow = means + (size_t)row * 8;
    const float* srow = sigmas + (size_t)row * 8;
    const float4 ma = *(const float4*)(mrow);
    const float4 mb = *(const float4*)(mrow + 4);
    const float4 sa = *(const float4*)(srow);
    const float4 sb = *(const float4*)(srow + 4);
    const float mm[8] = {ma.x, ma.y, ma.z, ma.w, mb.x, mb.y, mb.z, mb.w};
    const float sg[8] = {sa.x, sa.y, sa.z, sa.w, sb.x, sb.y, sb.z, sb.w};

    int idx[16];
#pragma unroll
    for (int j = 0; j < 8; ++j) {
        int i0 = (int)floorf(mm[j]);
        i0 = min(max(i0, 0), C_ - 1);
        idx[2 * j] = i0;
        idx[2 * j + 1] = min(i0 + 1, C_ - 1);
    }
    unsigned dupm = 0;
#pragma unroll
    for (int p = 1; p < 16; ++p) {
        bool d = false;
#pragma unroll
        for (int q = 0; q < 15; ++q)
            if (q < p) d = d || (idx[q] == idx[p]);
        if (d) dupm |= (1u << p);
    }
#pragma unroll
    for (int p = 0; p < 16; ++p) {
        const float fi = (float)idx[p];
        const bool dup = (dupm >> p) & 1u;
#pragma unroll
        for (int kk = 0; kk < 8; ++kk) {
            const float t = (fi - mm[kk]) / sg[kk];
            float val = dup ? 0.0f : expf(-0.5f * t * t);
#pragma unroll
            for (int off = 1; off < 64; off <<= 1)
                val += __shfl_xor(val, off);
            if (lane == 0)
                atomicAdd(&S[bh * 128 + p * 8 + kk], val);
        }
    }
}

// ---------------------------------------------------------------------------
// Fused QKV GEMM (MFMA bf16), 128x64 tiles -> 24x32 = 768 blocks (3.0/CU).
// N-tile = 64 = exactly one head: epilogue rows are 128B-contiguous in Out.
// ---------------------------------------------------------------------------
__global__ __launch_bounds__(256) void gemm_qkv_kernel(
    const uint16_t* __restrict__ xb, const uint16_t* __restrict__ Wall,
    uint16_t* __restrict__ Qt, uint16_t* __restrict__ Kt,
    uint16_t* __restrict__ Vt)
{
    const int K = E_;                       // 1024
    const int m0 = blockIdx.y * 128;
    const int n0 = blockIdx.x * 64;         // 0..1535
    const int z = n0 >> 9;
    uint16_t* __restrict__ Out = (z == 0) ? Qt : (z == 1) ? Kt : Vt;
    const int h = (n0 & 511) >> 6;          // single head per block

    // K-loop: As = smem[0..4096), Bs = smem[4096..6144)
    // epilogue: 128 x 72-stride bf16 tile in smem[0..9216)
    __shared__ __align__(16) uint16_t smem[9216];
    uint16_t* As = smem;
    uint16_t* Bs = smem + 4096;

    const int tid = threadIdx.x;
    const int w = tid >> 6, lane = tid & 63;

    f32x4 acc[2][4] = {};

    // staging: 12 chunks of 16 rows (8 A-chunks + 4 B-chunks); wave w: 3w..3w+2
    const uint16_t* gP[3];
    uint16_t* lP[3];
#pragma unroll
    for (int j = 0; j < 3; ++j) {
        const int ci = w * 3 + j;
        const int rr = (ci & 7) * 16 + (lane >> 2);   // works for both halves
        const int ko = (lane & 3) * 8;
        if (ci < 8) {
            gP[j] = xb + (size_t)(m0 + rr) * K + ko;
            lP[j] = &As[ci * 512];
        } else {
            const int cb = ci - 8;
            gP[j] = Wall + (size_t)(n0 + cb * 16 + (lane >> 2)) * K + ko;
            lP[j] = &Bs[cb * 512];
        }
    }

    const int fr = lane & 15;
    const int fk = (lane >> 4) * 8;

    for (int k0 = 0; k0 < K; k0 += 32) {
        __syncthreads();
        gload16(gP[0] + k0, lP[0]);
        gload16(gP[1] + k0, lP[1]);
        gload16(gP[2] + k0, lP[2]);
        __syncthreads();
        bf16x8 af[2], bf[4];
#pragma unroll
        for (int mt = 0; mt < 2; ++mt)
            af[mt] = *(const bf16x8*)&As[(w * 32 + mt * 16 + fr) * 32 + fk];
#pragma unroll
        for (int nt = 0; nt < 4; ++nt)
            bf[nt] = *(const bf16x8*)&Bs[(nt * 16 + fr) * 32 + fk];
#pragma unroll
        for (int mt = 0; mt < 2; ++mt)
#pragma unroll
            for (int nt = 0; nt < 4; ++nt)
                acc[mt][nt] = __builtin_amdgcn_mfma_f32_16x16x32_bf16(
                    af[mt], bf[nt], acc[mt][nt], 0, 0, 0);
    }

    // ---- epilogue: stage 128x64 bf16 tile (stride 72), stream coalesced ----
    __syncthreads();
#pragma unroll
    for (int mt = 0; mt < 2; ++mt)
#pragma unroll
        for (int nt = 0; nt < 4; ++nt) {
            const int col = nt * 16 + fr;
#pragma unroll
            for (int r = 0; r < 4; ++r) {
                const int rw = w * 32 + mt * 16 + (lane >> 4) * 4 + r;
                smem[rw * 72 + col] = f2bf(acc[mt][nt][r]);
            }
        }
    __syncthreads();
#pragma unroll
    for (int it = 0; it < 4; ++it) {
        const int j = it * 256 + tid;       // 0..1023 chunks of 8
        const int row = j >> 3, c8 = (j & 7) * 8;
        const int m = m0 + row;
        const int b = m >> 11, c = m & (C_ - 1);
        *(u16x8*)&Out[(((size_t)(b * H_ + h) * C_ + c) << 6) + c8] =
            *(const u16x8*)&smem[row * 72 + c8];
    }
}

// ---------------------------------------------------------------------------
// GEMM 2 (MFMA bf16), 128x64 tiles -> 16x32 = 512 blocks (2.0/CU).
// united (4096x512) @ Wu^T-rows (1024x512) + bu -> new_out fp32
// ---------------------------------------------------------------------------
__global__ __launch_bounds__(256) void gemm_out_kernel(
    const uint16_t* __restrict__ U, const uint16_t* __restrict__ Wut,
    const float* __restrict__ bu, float* __restrict__ out)
{
    const int K = HD_;                      // 512
    const int m0 = blockIdx.y * 128;
    const int n0 = blockIdx.x * 64;         // N=1024

    __shared__ __align__(16) uint16_t As[128 * 32];
    __shared__ __align__(16) uint16_t Bs[64 * 32];

    const int tid = threadIdx.x;
    const int w = tid >> 6, lane = tid & 63;

    f32x4 acc[2][4] = {};

    const uint16_t* gP[3];
    uint16_t* lP[3];
#pragma unroll
    for (int j = 0; j < 3; ++j) {
        const int ci = w * 3 + j;
        const int ko = (lane & 3) * 8;
        if (ci < 8) {
            gP[j] = U + (size_t)(m0 + ci * 16 + (lane >> 2)) * K + ko;
            lP[j] = &As[ci * 512];
        } else {
            const int cb = ci - 8;
            gP[j] = Wut + (size_t)(n0 + cb * 16 + (lane >> 2)) * K + ko;
            lP[j] = &Bs[cb * 512];
        }
    }

    const int fr = lane & 15;
    const int fk = (lane >> 4) * 8;

    for (int k0 = 0; k0 < K; k0 += 32) {
        __syncthreads();
        gload16(gP[0] + k0, lP[0]);
        gload16(gP[1] + k0, lP[1]);
        gload16(gP[2] + k0, lP[2]);
        __syncthreads();
        bf16x8 af[2], bf[4];
#pragma unroll
        for (int mt = 0; mt < 2; ++mt)
            af[mt] = *(const bf16x8*)&As[(w * 32 + mt * 16 + fr) * 32 + fk];
#pragma unroll
        for (int nt = 0; nt < 4; ++nt)
            bf[nt] = *(const bf16x8*)&Bs[(nt * 16 + fr) * 32 + fk];
#pragma unroll
        for (int mt = 0; mt < 2; ++mt)
#pragma unroll
            for (int nt = 0; nt < 4; ++nt)
                acc[mt][nt] = __builtin_amdgcn_mfma_f32_16x16x32_bf16(
                    af[mt], bf[nt], acc[mt][nt], 0, 0, 0);
    }

#pragma unroll
    for (int mt = 0; mt < 2; ++mt) {
#pragma unroll
        for (int nt = 0; nt < 4; ++nt) {
            const int n = n0 + nt * 16 + fr;
            const float bias = bu[n];
#pragma unroll
            for (int r = 0; r < 4; ++r) {
                const int m = m0 + w * 32 + mt * 16 + (lane >> 4) * 4 + r;
                out[(size_t)m * E_ + n] = acc[mt][nt][r] + bias;
            }
        }
    }
}

// ---------------------------------------------------------------------------
// attention core.  One wave per (b,h,c) row; LDS row scatter (per-wave
// region, block barriers only), nontemporal final row stream.
// ---------------------------------------------------------------------------
__global__ __launch_bounds__(256) void attn_kernel(
    const float* __restrict__ means, const float* __restrict__ sigmas,
    const float* __restrict__ values, const float* __restrict__ S,
    const uint16_t* __restrict__ Qt, const uint16_t* __restrict__ Kt,
    const uint16_t* __restrict__ Vt, uint16_t* __restrict__ united,
    float* __restrict__ attn)
{
    __shared__ float rowbuf[4][2048];
    const int w = threadIdx.x >> 6;
    const int lane = threadIdx.x & 63;
    const int row = blockIdx.x * 4 + w;
    const int bh = row >> 11;
    const int c = row & (C_ - 1);
    const int b = bh >> 3;
    const int h = bh & 7;

    const float* mrow = means + (size_t)row * 8;
    const float4 ma = *(const float4*)(mrow);
    const float4 mb = *(const float4*)(mrow + 4);
    const float mm[8] = {ma.x, ma.y, ma.z, ma.w, mb.x, mb.y, mb.z, mb.w};

    int idx[16];
#pragma unroll
    for (int j = 0; j < 8; ++j) {
        int i0 = (int)floorf(mm[j]);
        i0 = min(max(i0, 0), C_ - 1);
        idx[2 * j] = i0;
        idx[2 * j + 1] = min(i0 + 1, C_ - 1);
    }

    // ---- per-point weights on lanes 0..15 ----
    const int lp = lane & 15;
    int myidx = 0;
#pragma unroll
    for (int q = 0; q < 16; ++q)
        if (q == lp) myidx = idx[q];
    float wp = 0.0f;
    if (lane < 16) {
        bool dup = false;
#pragma unroll
        for (int q = 0; q < 15; ++q)
            dup = dup || ((q < lane) && (idx[q] == myidx));
        if (!dup) {
            const float* srow = sigmas + (size_t)row * 8;
            const float* vrow = values + (size_t)row * 8;
            const float4 sa = *(const float4*)(srow);
            const float4 sb = *(const float4*)(srow + 4);
            const float4 va = *(const float4*)(vrow);
            const float4 vb = *(const float4*)(vrow + 4);
            const float sg[8] = {sa.x, sa.y, sa.z, sa.w, sb.x, sb.y, sb.z, sb.w};
            const float vl[8] = {va.x, va.y, va.z, va.w, vb.x, vb.y, vb.z, vb.w};
            const float* Sp = S + bh * 128 + lane * 8;
            const float4 Sa = *(const float4*)(Sp);
            const float4 Sb = *(const float4*)(Sp + 4);
            const float Sv[8] = {Sa.x, Sa.y, Sa.z, Sa.w, Sb.x, Sb.y, Sb.z, Sb.w};
            const float fi = (float)myidx;
#pragma unroll
            for (int kk = 0; kk < 8; ++kk) {
                const float t = (fi - mm[kk]) / sg[kk];
                const float e = expf(-0.5f * t * t);
                wp = fmaf(vl[kk], e / (Sv[kk] + 1e-8f), wp);
            }
        }
    }

    // ---- dots in (p,g) layout: p = point, g covers dims [g*16, g*16+16) ----
    const int p = lane >> 2, g = lane & 3;
    int kidx = 0;
#pragma unroll
    for (int q = 0; q < 16; ++q)
        if (q == p) kidx = idx[q];

    const uint16_t* Qrow = Qt + ((size_t)row << 6);
    const uint16_t* Krow = Kt + ((((size_t)bh << 11) + kidx) << 6);
    const u16x8 qa = *(const u16x8*)(Qrow + g * 16);
    const u16x8 qb = *(const u16x8*)(Qrow + g * 16 + 8);
    const u16x8 ka = *(const u16x8*)(Krow + g * 16);
    const u16x8 kb = *(const u16x8*)(Krow + g * 16 + 8);
    float dot = 0.0f;
#pragma unroll
    for (int j = 0; j < 8; ++j) {
        dot = fmaf(bf2f(qa[j]), bf2f(ka[j]), dot);
        dot = fmaf(bf2f(qb[j]), bf2f(kb[j]), dot);
    }
    dot += __shfl_xor(dot, 1);
    dot += __shfl_xor(dot, 2);

    const float wvp = __shfl(wp, p);
    const float logit = wvp * dot;

    float mx = logit;
#pragma unroll
    for (int off = 4; off < 64; off <<= 1)
        mx = fmaxf(mx, __shfl_xor(mx, off));
    const float e = expf(logit - mx);
    float se = e;
#pragma unroll
    for (int off = 4; off < 64; off <<= 1)
        se += __shfl_xor(se, off);
    const float sm = e / se;

    float smv[16];
#pragma unroll
    for (int q = 0; q < 16; ++q)
        smv[q] = __shfl(sm, q * 4);
    const float myw = __shfl(sm, lp * 4);

    // ---- V combine (lane = d) ----
    const uint16_t* Vbh = Vt + ((size_t)bh << 17);
    float acc = 0.0f;
#pragma unroll
    for (int q = 0; q < 16; ++q)
        acc = fmaf(bf2f(Vbh[((size_t)idx[q] << 6) + lane]), smv[q], acc);
    united[((size_t)(b * C_ + c)) * HD_ + h * 64 + lane] = f2bf(acc);

    // ---- attentions row: zero LDS, scatter-add, nontemporal stream out ----
    const f32x4 z4 = {0.f, 0.f, 0.f, 0.f};
#pragma unroll
    for (int j = 0; j < 8; ++j)
        *(f32x4*)&rowbuf[w][(j * 64 + lane) * 4] = z4;
    __syncthreads();
    if (lane < 16) atomicAdd(&rowbuf[w][myidx], myw);
    __syncthreads();
    float* arow = attn + ((size_t)row << 11);
#pragma unroll
    for (int j = 0; j < 8; ++j) {
        const int o = (j * 64 + lane) * 4;
        __builtin_nontemporal_store(*(const f32x4*)&rowbuf[w][o], (f32x4*)&arow[o]);
    }
}

// ---------------------------------------------------------------------------
extern "C" void kernel_launch(void* const* d_in, const int* in_sizes, int n_in,
                              void* d_out, int out_size, void* d_ws,
                              size_t ws_size, hipStream_t stream) {
    const float* x      = (const float*)d_in[0];
    const float* means  = (const float*)d_in[2];
    const float* sigmas = (const float*)d_in[3];
    const float* values = (const float*)d_in[4];
    const float* Wk     = (const float*)d_in[5];
    const float* Wq     = (const float*)d_in[6];
    const float* Wv     = (const float*)d_in[7];
    const float* Wu     = (const float*)d_in[8];
    const float* bu     = (const float*)d_in[9];

    float* out  = (float*)d_out;
    float* attn = out + (size_t)M_ * E_;

    uint16_t* wsp = (uint16_t*)d_ws;
    uint16_t* xb     = wsp;                              // 4194304
    uint16_t* Wall   = xb + 4194304;                     // 1572864 (1536x1024)
    uint16_t* Wut    = Wall + 1572864;                   // 524288
    uint16_t* Qt     = Wut + 524288;                     // 2097152
    uint16_t* Kt     = Qt + 2097152;
    uint16_t* Vt     = Kt + 2097152;
    uint16_t* united = Vt + 2097152;                     // 2097152
    float*    S      = (float*)(united + 2097152);       // 2048 floats

    (void)hipMemsetAsync(S, 0, 2048 * sizeof(float), stream);

    prep_kernel<<<4224, 256, 0, stream>>>(
        x, Wq, Wk, Wv, Wu, means, sigmas, xb, Wall, Wut, S);
    gemm_qkv_kernel<<<dim3(24, 32), 256, 0, stream>>>(xb, Wall, Qt, Kt, Vt);
    attn_kernel<<<ROWS_ / 4, 256, 0, stream>>>(
        means, sigmas, values, S, Qt, Kt, Vt, united, attn);
    gemm_out_kernel<<<dim3(16, 32), 256, 0, stream>>>(united, Wut, bu, out);
}